// Round 1
// baseline (333.375 us; speedup 1.0000x reference)
//
#include <hip/hip_runtime.h>

// LSTM cell fused, round 4: prep kernel rewritten for full 16B/lane
// vectorization. Pack: Z/H in disjoint block ranges (no divergence),
// 2x float4 in -> bf16x8 out per thread. Transpose: 64x64 tiles,
// float4 global reads -> f32 LDS [64][65] -> bf16x8 16B stores
// (was scalar 4B loads / 2B stores). GEMM unchanged (785 TF, at the
// 128^2 2-barrier structural ceiling; 256^2 8-phase is the next step).

#define BDIM 8192
#define KDIM 2048
#define NDIM 1024
#define NCAT 4096

typedef __bf16 bf16x8 __attribute__((ext_vector_type(8)));
typedef __bf16 bf16x4 __attribute__((ext_vector_type(4)));
typedef float  f32x4  __attribute__((ext_vector_type(4)));

__device__ __forceinline__ void async_cp16(const void* g, void* l) {
    __builtin_amdgcn_global_load_lds((__attribute__((address_space(1))) void*)g,
                                     (__attribute__((address_space(3))) void*)l,
                                     16, 0, 0);
}

__device__ __forceinline__ float sigm(float x) { return 1.f / (1.f + __expf(-x)); }
__device__ __forceinline__ float tanh_fast(float x) { return 1.f - 2.f / (1.f + __expf(2.f * x)); }

// ---------------- prep: A pack + weight transpose, fully vectorized ----------------
// blocks [0, 4096):     Z  -> A cols [0, 1024)      (bf16 cast, 32B->16B per lane)
// blocks [4096, 8192):  H  -> A cols [1024, 2048)
// blocks [8192, 10240): W transpose, 64x64 f32 tile per block -> Wt bf16
__global__ __launch_bounds__(256)
void prep_kernel(const float* __restrict__ Z, const float* __restrict__ H,
                 const float* __restrict__ Wi, const float* __restrict__ Wf,
                 const float* __restrict__ Wo, const float* __restrict__ Wg,
                 __bf16* __restrict__ A, __bf16* __restrict__ Wt) {
    __shared__ float t[64][65];
    const int bid = blockIdx.x;
    const int tid = threadIdx.x;

    if (bid < 8192) {
        // ---- pack: each thread converts 8 f32 -> 8 bf16 ----
        const bool isZ = (bid < 4096);
        const int idx  = (isZ ? bid : bid - 4096) * 256 + tid; // bf16x8 unit id
        const int row  = idx >> 7;        // 128 units per 1024-float row
        const int q8   = idx & 127;
        const float* src = isZ ? Z : H;
        const float4* p = (const float4*)src + ((size_t)row << 8) + q8 * 2;
        float4 v0 = p[0], v1 = p[1];
        bf16x8 o = { (__bf16)v0.x, (__bf16)v0.y, (__bf16)v0.z, (__bf16)v0.w,
                     (__bf16)v1.x, (__bf16)v1.y, (__bf16)v1.z, (__bf16)v1.w };
        const int col8 = isZ ? q8 : (q8 + 128);
        ((bf16x8*)A)[(size_t)row * 256 + col8] = o;
    } else {
        // ---- transpose: gate g, 64(k) x 64(n) tile ----
        const int id  = bid - 8192;          // [0, 2048)
        const int g   = id >> 9;             // 512 tiles per gate
        const int rem = id & 511;
        const int k0  = (rem & 31) * 64;     // 32 k-tiles
        const int n0  = (rem >> 5) * 64;     // 16 n-tiles
        const float* W = (g == 0) ? Wi : (g == 1) ? Wf : (g == 2) ? Wo : Wg;

        // load 64 rows x 16 float4 (fully coalesced, 16B/lane)
        const int c4 = tid & 15, r0 = tid >> 4;
        #pragma unroll
        for (int it = 0; it < 4; ++it) {
            const int r = r0 + it * 16;
            float4 v = ((const float4*)W)[(size_t)(k0 + r) * 256 + (n0 >> 2) + c4];
            t[r][c4 * 4 + 0] = v.x;
            t[r][c4 * 4 + 1] = v.y;
            t[r][c4 * 4 + 2] = v.z;
            t[r][c4 * 4 + 3] = v.w;
        }
        __syncthreads();

        // write out transposed: 64 n-rows x 8 bf16x8 chunks (16B/lane,
        // 8 consecutive lanes = 128B contiguous in one Wt row)
        const int kc = tid & 7, nn0 = tid >> 3;
        #pragma unroll
        for (int j = 0; j < 2; ++j) {
            const int n    = nn0 + j * 32;
            const int ncat = n0 + n;
            const size_t outRow = (size_t)(ncat >> 5) * 128 + g * 32 + (ncat & 31);
            bf16x8 o;
            #pragma unroll
            for (int kk = 0; kk < 8; ++kk) o[kk] = (__bf16)t[kc * 8 + kk][n];
            *(bf16x8*)(Wt + outRow * KDIM + k0 + kc * 8) = o;
        }
    }
}

// ---------------- 128x128 GEMM + fused LSTM epilogue (unchanged) ----------------
// LDS layout (32KB): As = 2 halves x [128 rows x 32 k] bf16 (8KB each),
// Bs likewise at +16KB. Each half uses the verified BK=32 XOR-chunk swizzle
// (row stride 64B -> row parity spreads banks; 0 conflicts measured).
// Epilogue overlays LDS with Ep[32][132] f32 (16.9KB), 4 row-chunks.
__global__ __launch_bounds__(256, 4)
void lstm_gemm_kernel(const __bf16* __restrict__ A, const __bf16* __restrict__ Wt,
                      const float* __restrict__ b_i, const float* __restrict__ b_f,
                      const float* __restrict__ b_o, const float* __restrict__ b_g,
                      const float* __restrict__ c_prev, float* __restrict__ out) {
    __shared__ char smem[32768];
    __bf16* As = (__bf16*)smem;               // 16 KB (2 x 8KB halves)
    __bf16* Bs = (__bf16*)(smem + 16384);     // 16 KB
    float*  Ep = (float*)smem;                // epilogue overlay 32x132 f32

    const int tid  = threadIdx.x;
    const int wave = tid >> 6;
    const int lane = tid & 63;
    const int wr = wave >> 1, wc = wave & 1;

    // XCD swizzle: assume consecutive blockIdx round-robin XCDs. XCD x owns
    // bx in [x*4, x*4+4) (2MB of Wt -> L2-resident), sweeping all by.
    const int bid = blockIdx.x;
    const int bx = (bid & 7) * 4 + ((bid >> 3) & 3);
    const int by = bid >> 5;
    const int m0 = by * 128;
    const int ncat0 = bx * 128;

    // staging: group g = wave*2+i covers rows [g*16, g*16+16) of one half;
    // lane l -> row g*16 + (l>>2), LDS chunk l&3, global chunk (l&3)^((l>>3)&3).
    const int srow   = lane >> 2;
    const int schunk = (lane & 3) ^ ((lane >> 3) & 3);
    const __bf16* Ag[2]; __bf16* Al[2];
    const __bf16* Bg[2]; __bf16* Bl[2];
    #pragma unroll
    for (int i = 0; i < 2; ++i) {
        int grp = wave * 2 + i;
        Ag[i] = A  + (size_t)(m0    + grp * 16 + srow) * KDIM + schunk * 8;
        Bg[i] = Wt + (size_t)(ncat0 + grp * 16 + srow) * KDIM + schunk * 8;
        Al[i] = As + grp * 512;
        Bl[i] = Bs + grp * 512;
    }

    // fragment geometry within a half: A[m=l15][k=quad*8+j], swizzled chunk
    const int l15  = lane & 15;
    const int quad = lane >> 4;
    const int ksw  = (quad ^ ((l15 >> 1) & 3)) * 8;
    int aoff[4], boff[4];
    #pragma unroll
    for (int t = 0; t < 4; ++t) {
        aoff[t] = (wr * 64 + t * 16 + l15) * 32 + ksw;
        boff[t] = (wc * 64 + t * 16 + l15) * 32 + ksw;
    }

    f32x4 acc[4][4];
    #pragma unroll
    for (int i = 0; i < 4; ++i)
        #pragma unroll
        for (int j = 0; j < 4; ++j) acc[i][j] = (f32x4){0.f, 0.f, 0.f, 0.f};

    for (int k0 = 0; k0 < KDIM; k0 += 64) {
        #pragma unroll
        for (int h = 0; h < 2; ++h)
            #pragma unroll
            for (int i = 0; i < 2; ++i) {
                async_cp16(Ag[i] + k0 + h * 32, Al[i] + h * 4096);
                async_cp16(Bg[i] + k0 + h * 32, Bl[i] + h * 4096);
            }
        __syncthreads();

        #pragma unroll
        for (int h = 0; h < 2; ++h) {
            bf16x8 af[4], bfr[4];
            #pragma unroll
            for (int t = 0; t < 4; ++t) af[t]  = *(const bf16x8*)(As + h * 4096 + aoff[t]);
            #pragma unroll
            for (int t = 0; t < 4; ++t) bfr[t] = *(const bf16x8*)(Bs + h * 4096 + boff[t]);
            #pragma unroll
            for (int mt = 0; mt < 4; ++mt)
                #pragma unroll
                for (int nt = 0; nt < 4; ++nt)
                    acc[mt][nt] = __builtin_amdgcn_mfma_f32_16x16x32_bf16(af[mt], bfr[nt], acc[mt][nt], 0, 0, 0);
        }
        __syncthreads();
    }

    // --- epilogue: 4 chunks of 32 rows ---
    // wave cat-col = wc*64 + nt*16 + l15 -> gate = wc*2 + (nt>>1)
    const float* bias_lo = (wc == 0) ? b_i : b_o;
    const float* bias_hi = (wc == 0) ? b_f : b_g;
    float bv[4];
    bv[0] = bias_lo[bx * 32 + l15];
    bv[1] = bias_lo[bx * 32 + 16 + l15];
    bv[2] = bias_hi[bx * 32 + l15];
    bv[3] = bias_hi[bx * 32 + 16 + l15];

    #pragma unroll
    for (int c = 0; c < 4; ++c) {     // chunk c: tile rows [c*32, c*32+32)
        __syncthreads();
        if (wr == (c >> 1)) {
            #pragma unroll
            for (int mi = 0; mi < 2; ++mi) {
                int mt = (c & 1) * 2 + mi;
                #pragma unroll
                for (int nt = 0; nt < 4; ++nt)
                    #pragma unroll
                    for (int r = 0; r < 4; ++r)
                        Ep[(mi * 16 + quad * 4 + r) * 132 + wc * 64 + nt * 16 + l15] =
                            acc[mt][nt][r] + bv[nt];
            }
        }
        __syncthreads();

        #pragma unroll
        for (int e = 0; e < 4; ++e) {
            int idx = tid + e * 256;          // 0..1023 over 32 rows x 32 cols
            int row = idx >> 5, n = idx & 31;
            float gi = sigm(Ep[row * 132 + n]);
            float gf = sigm(Ep[row * 132 + 32 + n]);
            float go = sigm(Ep[row * 132 + 64 + n]);
            float gg = tanh_fast(Ep[row * 132 + 96 + n]);
            size_t pos = (size_t)(m0 + c * 32 + row) * NDIM + bx * 32 + n;
            float cp = c_prev[pos];
            float cv = gf * cp + gi * gg;
            out[pos] = go * tanh_fast(cv);                 // h
            out[(size_t)BDIM * NDIM + pos] = cv;           // c
        }
    }
}

extern "C" void kernel_launch(void* const* d_in, const int* in_sizes, int n_in,
                              void* d_out, int out_size, void* d_ws, size_t ws_size,
                              hipStream_t stream) {
    const float* Z  = (const float*)d_in[0];
    const float* H  = (const float*)d_in[1];
    const float* Cp = (const float*)d_in[2];
    const float* Wi = (const float*)d_in[3];
    const float* bi = (const float*)d_in[4];
    const float* Wf = (const float*)d_in[5];
    const float* bf = (const float*)d_in[6];
    const float* Wo = (const float*)d_in[7];
    const float* bo = (const float*)d_in[8];
    const float* Wg = (const float*)d_in[9];
    const float* bg = (const float*)d_in[10];

    __bf16* Acomb = (__bf16*)d_ws;                              // 32 MB
    __bf16* Wt    = (__bf16*)((char*)d_ws + (size_t)33554432);  // 16 MB

    prep_kernel<<<10240, 256, 0, stream>>>(Z, H, Wi, Wf, Wo, Wg, Acomb, Wt);
    lstm_gemm_kernel<<<dim3(NCAT / 128 * BDIM / 128), 256, 0, stream>>>(
        Acomb, Wt, bi, bf, bo, bg, Cp, (float*)d_out);
}

// Round 2
// 324.835 us; speedup vs baseline: 1.0263x; 1.0263x over previous
//
#include <hip/hip_runtime.h>

// LSTM cell fused, round 5: GEMM ported to the 256x256 8-phase schedule
// (T2 st_16x32 LDS swizzle + T3/T4 counted vmcnt(4) + T5 setprio).
// 512 threads (2x4 waves), BK=64, 2-deep LDS double buffer = 128KB dynamic.
// Per tile: 4 phases = C-quadrants; stages ph0:(t+1)A-h1, ph1:(t+1)B-h1,
// ph3:(t+2)A-h0+B-h0; one vmcnt(4) per tile (vmcnt(0) for last 2 tiles).
// prep_kernel byte-identical to round 4 (its ~156us is access-pattern-
// invariant; GEMM speedup will surface it in top-5 counters).

#define BDIM 8192
#define KDIM 2048
#define NDIM 1024
#define NCAT 4096
#define NT   32      // KDIM / 64

typedef __bf16 bf16x8 __attribute__((ext_vector_type(8)));
typedef __bf16 bf16x4 __attribute__((ext_vector_type(4)));
typedef float  f32x4  __attribute__((ext_vector_type(4)));

__device__ __forceinline__ void async_cp16(const void* g, void* l) {
    __builtin_amdgcn_global_load_lds((__attribute__((address_space(1))) void*)g,
                                     (__attribute__((address_space(3))) void*)l,
                                     16, 0, 0);
}

__device__ __forceinline__ float sigm(float x) { return 1.f / (1.f + __expf(-x)); }
__device__ __forceinline__ float tanh_fast(float x) { return 1.f - 2.f / (1.f + __expf(2.f * x)); }

#define BARM asm volatile("s_barrier" ::: "memory")

// ---------------- prep: A pack + weight transpose (unchanged) ----------------
__global__ __launch_bounds__(256)
void prep_kernel(const float* __restrict__ Z, const float* __restrict__ H,
                 const float* __restrict__ Wi, const float* __restrict__ Wf,
                 const float* __restrict__ Wo, const float* __restrict__ Wg,
                 __bf16* __restrict__ A, __bf16* __restrict__ Wt) {
    __shared__ float t[64][65];
    const int bid = blockIdx.x;
    const int tid = threadIdx.x;

    if (bid < 8192) {
        const bool isZ = (bid < 4096);
        const int idx  = (isZ ? bid : bid - 4096) * 256 + tid;
        const int row  = idx >> 7;
        const int q8   = idx & 127;
        const float* src = isZ ? Z : H;
        const float4* p = (const float4*)src + ((size_t)row << 8) + q8 * 2;
        float4 v0 = p[0], v1 = p[1];
        bf16x8 o = { (__bf16)v0.x, (__bf16)v0.y, (__bf16)v0.z, (__bf16)v0.w,
                     (__bf16)v1.x, (__bf16)v1.y, (__bf16)v1.z, (__bf16)v1.w };
        const int col8 = isZ ? q8 : (q8 + 128);
        ((bf16x8*)A)[(size_t)row * 256 + col8] = o;
    } else {
        const int id  = bid - 8192;
        const int g   = id >> 9;
        const int rem = id & 511;
        const int k0  = (rem & 31) * 64;
        const int n0  = (rem >> 5) * 64;
        const float* W = (g == 0) ? Wi : (g == 1) ? Wf : (g == 2) ? Wo : Wg;

        const int c4 = tid & 15, r0 = tid >> 4;
        #pragma unroll
        for (int it = 0; it < 4; ++it) {
            const int r = r0 + it * 16;
            float4 v = ((const float4*)W)[(size_t)(k0 + r) * 256 + (n0 >> 2) + c4];
            t[r][c4 * 4 + 0] = v.x;
            t[r][c4 * 4 + 1] = v.y;
            t[r][c4 * 4 + 2] = v.z;
            t[r][c4 * 4 + 3] = v.w;
        }
        __syncthreads();

        const int kc = tid & 7, nn0 = tid >> 3;
        #pragma unroll
        for (int j = 0; j < 2; ++j) {
            const int n    = nn0 + j * 32;
            const int ncat = n0 + n;
            const size_t outRow = (size_t)(ncat >> 5) * 128 + g * 32 + (ncat & 31);
            bf16x8 o;
            #pragma unroll
            for (int kk = 0; kk < 8; ++kk) o[kk] = (__bf16)t[kc * 8 + kk][n];
            *(bf16x8*)(Wt + outRow * KDIM + k0 + kc * 8) = o;
        }
    }
}

// ---------------- 256x256 8-phase GEMM + fused LSTM epilogue ----------------
__global__ __launch_bounds__(512, 2)
void lstm_gemm_kernel(const __bf16* __restrict__ A, const __bf16* __restrict__ Wt,
                      const float* __restrict__ b_i, const float* __restrict__ b_f,
                      const float* __restrict__ b_o, const float* __restrict__ b_g,
                      const float* __restrict__ c_prev, float* __restrict__ out) {
    extern __shared__ char smem[];   // 128KB: buf{0,1} x { A 2x16KB | B 2x16KB }

    const int tid  = threadIdx.x;
    const int wave = tid >> 6;
    const int lane = tid & 63;
    const int wm   = wave >> 2;      // 0..1  (m half: 128 rows each)
    const int wn   = wave & 3;       // 0..3  (64 cat cols each)
    const int l15  = lane & 15;
    const int quad = lane >> 4;

    // XCD swizzle: 512 blocks, 8 XCDs -> 64 blocks/XCD = 2 cat-panels x 32 by
    const int bid = blockIdx.x;
    const int bxc = (bid & 7) * 2 + (bid >> 8);   // cat-tile [0,16)
    const int by  = (bid >> 3) & 31;              // m-tile   [0,32)
    const int m0   = by * 256;
    const int cat0 = bxc * 256;
    const int n0   = bxc * 64;

    // ---- staging: half-tile [128][64]bf16 = 16KB; 2 gloads/thread.
    // instr (wave,i): lane -> local row i*64 + wave*8 + (lane>>3), lds chunk lane&7.
    // st_16x32 swizzle: tile chunk = (lane&7) ^ (((lane>>5)&1)<<1)  (bit9->bit5)
    const int grow   = wave * 8 + (lane >> 3);
    const int schunk = (lane & 7) ^ (((lane >> 5) & 1) << 1);
    const __bf16* Ags = A  + (size_t)(m0   + grow) * KDIM + schunk * 8;
    const __bf16* Bgs = Wt + (size_t)(cat0 + grow) * KDIM + schunk * 8;
    char* ldsw = smem + wave * 1024;

#define STG(o, h, kt, b) do { \
    const __bf16* gp_ = ((o) ? Bgs : Ags) + (size_t)(h) * 128 * KDIM + (size_t)(kt) * 64; \
    char* lp_ = ldsw + (b) * 65536 + (o) * 32768 + (h) * 16384; \
    async_cp16(gp_, lp_); \
    async_cp16(gp_ + (size_t)64 * KDIM, lp_ + 8192); \
} while (0)

    // ---- fragment read offsets (swizzled): row r, want k-chunk c ->
    // lds chunk c ^ (((r>>2)&1)<<1); here (r>>2)&1 == (l15>>2)&1 for all frags.
    const int xorr = ((l15 >> 2) & 1) << 1;
    const int cA0  = (quad ^ xorr) * 16;          // ks=0
    const int cA1  = ((quad + 4) ^ xorr) * 16;    // ks=1
    const int aoff0 = wm * 16384 + l15 * 128;                              // A base (mt=0)
    const int boff0 = 32768 + (wn >> 1) * 16384 + ((wn & 1) * 64 + l15) * 128; // B base (nt=0)

    f32x4 acc[8][4];
    #pragma unroll
    for (int i = 0; i < 8; ++i)
        #pragma unroll
        for (int j = 0; j < 4; ++j) acc[i][j] = (f32x4){0.f, 0.f, 0.f, 0.f};

    bf16x8 af[4][2];   // current m-quadrant (4 frags x 2 ks)
    bf16x8 bf[4][2];   // all 4 n-frags x 2 ks

    auto LDA = [&](int mh, int bufb) {
        const char* p = smem + bufb + aoff0 + mh * 8192;
        #pragma unroll
        for (int m = 0; m < 4; ++m) {
            af[m][0] = *(const bf16x8*)(p + m * 2048 + cA0);
            af[m][1] = *(const bf16x8*)(p + m * 2048 + cA1);
        }
    };
    auto LDB = [&](int nh, int bufb) {
        const char* p = smem + bufb + boff0 + nh * 4096;
        #pragma unroll
        for (int n = 0; n < 2; ++n) {
            bf[nh * 2 + n][0] = *(const bf16x8*)(p + n * 2048 + cA0);
            bf[nh * 2 + n][1] = *(const bf16x8*)(p + n * 2048 + cA1);
        }
    };
    auto MMA = [&](int mh, int nh) {
        #pragma unroll
        for (int m = 0; m < 4; ++m)
            #pragma unroll
            for (int n = 0; n < 2; ++n) {
                acc[mh * 4 + m][nh * 2 + n] = __builtin_amdgcn_mfma_f32_16x16x32_bf16(
                    af[m][0], bf[nh * 2 + n][0], acc[mh * 4 + m][nh * 2 + n], 0, 0, 0);
                acc[mh * 4 + m][nh * 2 + n] = __builtin_amdgcn_mfma_f32_16x16x32_bf16(
                    af[m][1], bf[nh * 2 + n][1], acc[mh * 4 + m][nh * 2 + n], 0, 0, 0);
            }
    };

    // ---- prologue: tile0 fully + tile1 h0 halves; keep tile1-h0 in flight
    STG(0, 0, 0, 0); STG(1, 0, 0, 0); STG(0, 1, 0, 0); STG(1, 1, 0, 0);
    STG(0, 0, 1, 1); STG(1, 0, 1, 1);
    asm volatile("s_waitcnt vmcnt(4)" ::: "memory");   // tile0 landed
    BARM;

    #pragma unroll 2
    for (int t = 0; t < NT; ++t) {
        const int b    = t & 1;
        const int bufb = b * 65536;
        // phase 0: quadrant (mh0, nh0); stage (t+1) A-h1 -> other buf
        LDA(0, bufb); LDB(0, bufb);
        if (t + 1 < NT) STG(0, 1, t + 1, b ^ 1);
        BARM; asm volatile("s_waitcnt lgkmcnt(0)" ::: "memory");
        __builtin_amdgcn_s_setprio(1); MMA(0, 0); __builtin_amdgcn_s_setprio(0);
        BARM;
        // phase 1: (mh0, nh1); stage (t+1) B-h1
        LDB(1, bufb);
        if (t + 1 < NT) STG(1, 1, t + 1, b ^ 1);
        BARM; asm volatile("s_waitcnt lgkmcnt(0)" ::: "memory");
        __builtin_amdgcn_s_setprio(1); MMA(0, 1); __builtin_amdgcn_s_setprio(0);
        BARM;
        // phase 2: (mh1, nh0); no stage (A-h0/B-h0 still being read this tile)
        LDA(1, bufb);
        BARM; asm volatile("s_waitcnt lgkmcnt(0)" ::: "memory");
        __builtin_amdgcn_s_setprio(1); MMA(1, 0); __builtin_amdgcn_s_setprio(0);
        BARM;
        // phase 3: (mh1, nh1); stage (t+2) h0 halves into cur buf (now free);
        // boundary vmcnt BEFORE barrier -> publishes tile t+1 cross-wave.
        if (t + 2 < NT) { STG(0, 0, t + 2, b); STG(1, 0, t + 2, b); }
        if (t < NT - 2) { asm volatile("s_waitcnt vmcnt(4)" ::: "memory"); }
        else            { asm volatile("s_waitcnt vmcnt(0)" ::: "memory"); }
        BARM;
        __builtin_amdgcn_s_setprio(1); MMA(1, 1); __builtin_amdgcn_s_setprio(0);
        BARM;
    }

    // ---- epilogue: 4 passes of 64 m-rows; Ep[64][258] f32 (66KB, 2-way banks)
    float* Ep = (float*)smem;
    const int nn = tid & 63;
    const float bvi = b_i[n0 + nn], bvf = b_f[n0 + nn];
    const float bvo = b_o[n0 + nn], bvg = b_g[n0 + nn];
    // writer col per n-frag: gate g = (wn&1)*2 + (nt>>1), n_rel = (wn>>1)*32 + (nt&1)*16 + l15
    int colW[4];
    #pragma unroll
    for (int nt = 0; nt < 4; ++nt)
        colW[nt] = ((wn & 1) * 2 + (nt >> 1)) * 64 + (wn >> 1) * 32 + (nt & 1) * 16 + l15;

    #pragma unroll
    for (int ch = 0; ch < 4; ++ch) {
        BARM;
        if (wm == (ch >> 1)) {
            #pragma unroll
            for (int mi = 0; mi < 4; ++mi) {
                const int mt = (ch & 1) * 4 + mi;
                #pragma unroll
                for (int nt = 0; nt < 4; ++nt)
                    #pragma unroll
                    for (int r = 0; r < 4; ++r)
                        Ep[(mi * 16 + quad * 4 + r) * 258 + colW[nt]] = acc[mt][nt][r];
            }
        }
        BARM;
        #pragma unroll
        for (int e = 0; e < 8; ++e) {
            const int row = e * 8 + wave;
            const float gi = sigm(Ep[row * 258 + nn] + bvi);
            const float gf = sigm(Ep[row * 258 + 64 + nn] + bvf);
            const float go = sigm(Ep[row * 258 + 128 + nn] + bvo);
            const float gg = tanh_fast(Ep[row * 258 + 192 + nn] + bvg);
            const size_t pos = (size_t)(m0 + ch * 64 + row) * NDIM + n0 + nn;
            const float cp = c_prev[pos];
            const float cv = gf * cp + gi * gg;
            out[pos] = go * tanh_fast(cv);                 // h
            out[(size_t)BDIM * NDIM + pos] = cv;           // c
        }
    }
#undef STG
}

extern "C" void kernel_launch(void* const* d_in, const int* in_sizes, int n_in,
                              void* d_out, int out_size, void* d_ws, size_t ws_size,
                              hipStream_t stream) {
    const float* Z  = (const float*)d_in[0];
    const float* H  = (const float*)d_in[1];
    const float* Cp = (const float*)d_in[2];
    const float* Wi = (const float*)d_in[3];
    const float* bi = (const float*)d_in[4];
    const float* Wf = (const float*)d_in[5];
    const float* bf = (const float*)d_in[6];
    const float* Wo = (const float*)d_in[7];
    const float* bo = (const float*)d_in[8];
    const float* Wg = (const float*)d_in[9];
    const float* bg = (const float*)d_in[10];

    __bf16* Acomb = (__bf16*)d_ws;                              // 32 MB
    __bf16* Wt    = (__bf16*)((char*)d_ws + (size_t)33554432);  // 16 MB

    static bool cfg = false;
    if (!cfg) {
        hipFuncSetAttribute(reinterpret_cast<const void*>(lstm_gemm_kernel),
                            hipFuncAttributeMaxDynamicSharedMemorySize, 131072);
        cfg = true;
    }

    prep_kernel<<<10240, 256, 0, stream>>>(Z, H, Wi, Wf, Wo, Wg, Acomb, Wt);
    lstm_gemm_kernel<<<512, 512, 131072, stream>>>(
        Acomb, Wt, bi, bf, bo, bg, Cp, (float*)d_out);
}

// Round 3
// 319.693 us; speedup vs baseline: 1.0428x; 1.0161x over previous
//
#include <hip/hip_runtime.h>

// LSTM cell fused, round 6: 8-phase 256x256 schedule kept; LDS geometry
// reverted to the round-3 PROVEN zero-conflict layout: each 16KB half-tile
// = 2 panels [128 rows][32 k] bf16 (64B rows), read swizzle
// chunk ^= (row>>1)&3, staging source pre-swizzled (tid&3)^((tid>>3)&3).
// Round-5's 128B-row + 1-bit XOR measured 1.36e7 conflicts (4.3/read) and
// nullified the 8-phase gain (T2 gates T3/T4/T5). Phases/vmcnt/setprio
// unchanged; epilogue barriers hardened to __syncthreads().

#define BDIM 8192
#define KDIM 2048
#define NDIM 1024
#define NCAT 4096
#define NT   32      // KDIM / 64

typedef __bf16 bf16x8 __attribute__((ext_vector_type(8)));
typedef float  f32x4  __attribute__((ext_vector_type(4)));

__device__ __forceinline__ void async_cp16(const void* g, void* l) {
    __builtin_amdgcn_global_load_lds((__attribute__((address_space(1))) void*)g,
                                     (__attribute__((address_space(3))) void*)l,
                                     16, 0, 0);
}

__device__ __forceinline__ float sigm(float x) { return 1.f / (1.f + __expf(-x)); }
__device__ __forceinline__ float tanh_fast(float x) { return 1.f - 2.f / (1.f + __expf(2.f * x)); }

#define BARM asm volatile("s_barrier" ::: "memory")

// ---------------- prep: A pack + weight transpose (unchanged) ----------------
__global__ __launch_bounds__(256)
void prep_kernel(const float* __restrict__ Z, const float* __restrict__ H,
                 const float* __restrict__ Wi, const float* __restrict__ Wf,
                 const float* __restrict__ Wo, const float* __restrict__ Wg,
                 __bf16* __restrict__ A, __bf16* __restrict__ Wt) {
    __shared__ float t[64][65];
    const int bid = blockIdx.x;
    const int tid = threadIdx.x;

    if (bid < 8192) {
        const bool isZ = (bid < 4096);
        const int idx  = (isZ ? bid : bid - 4096) * 256 + tid;
        const int row  = idx >> 7;
        const int q8   = idx & 127;
        const float* src = isZ ? Z : H;
        const float4* p = (const float4*)src + ((size_t)row << 8) + q8 * 2;
        float4 v0 = p[0], v1 = p[1];
        bf16x8 o = { (__bf16)v0.x, (__bf16)v0.y, (__bf16)v0.z, (__bf16)v0.w,
                     (__bf16)v1.x, (__bf16)v1.y, (__bf16)v1.z, (__bf16)v1.w };
        const int col8 = isZ ? q8 : (q8 + 128);
        ((bf16x8*)A)[(size_t)row * 256 + col8] = o;
    } else {
        const int id  = bid - 8192;
        const int g   = id >> 9;
        const int rem = id & 511;
        const int k0  = (rem & 31) * 64;
        const int n0  = (rem >> 5) * 64;
        const float* W = (g == 0) ? Wi : (g == 1) ? Wf : (g == 2) ? Wo : Wg;

        const int c4 = tid & 15, r0 = tid >> 4;
        #pragma unroll
        for (int it = 0; it < 4; ++it) {
            const int r = r0 + it * 16;
            float4 v = ((const float4*)W)[(size_t)(k0 + r) * 256 + (n0 >> 2) + c4];
            t[r][c4 * 4 + 0] = v.x;
            t[r][c4 * 4 + 1] = v.y;
            t[r][c4 * 4 + 2] = v.z;
            t[r][c4 * 4 + 3] = v.w;
        }
        __syncthreads();

        const int kc = tid & 7, nn0 = tid >> 3;
        #pragma unroll
        for (int j = 0; j < 2; ++j) {
            const int n    = nn0 + j * 32;
            const int ncat = n0 + n;
            const size_t outRow = (size_t)(ncat >> 5) * 128 + g * 32 + (ncat & 31);
            bf16x8 o;
            #pragma unroll
            for (int kk = 0; kk < 8; ++kk) o[kk] = (__bf16)t[kc * 8 + kk][n];
            *(bf16x8*)(Wt + outRow * KDIM + k0 + kc * 8) = o;
        }
    }
}

// ---------------- 256x256 8-phase GEMM + fused LSTM epilogue ----------------
// LDS per buffer (64KB): A half h at h*16384 = { panel ks0 [128][32] 8KB,
// panel ks1 at +8192 }; B at +32768 likewise. Panel byte addr:
// row*64 + (chunk ^ ((row>>1)&3))*16  -- round-3 proven 0-conflict.
__global__ __launch_bounds__(512, 2)
void lstm_gemm_kernel(const __bf16* __restrict__ A, const __bf16* __restrict__ Wt,
                      const float* __restrict__ b_i, const float* __restrict__ b_f,
                      const float* __restrict__ b_o, const float* __restrict__ b_g,
                      const float* __restrict__ c_prev, float* __restrict__ out) {
    extern __shared__ char smem[];   // 128KB: buf{0,1} x { A 2x16KB | B 2x16KB }

    const int tid  = threadIdx.x;
    const int wave = tid >> 6;
    const int lane = tid & 63;
    const int wm   = wave >> 2;      // 0..1  (m half: 128 rows each)
    const int wn   = wave & 3;       // 0..3  (64 cat cols each)
    const int l15  = lane & 15;
    const int quad = lane >> 4;

    // XCD swizzle: 512 blocks, 8 XCDs -> 64 blocks/XCD = 2 cat-panels x 32 by
    const int bid = blockIdx.x;
    const int bxc = (bid & 7) * 2 + (bid >> 8);   // cat-tile [0,16)
    const int by  = (bid >> 3) & 31;              // m-tile   [0,32)
    const int m0   = by * 256;
    const int cat0 = bxc * 256;
    const int n0   = bxc * 64;

    // ---- staging: panel [128][32] = 8KB = 512thr x 16B, 1 load/thread.
    // thread tid -> panel byte tid*16: row tid>>2, lds chunk tid&3;
    // inverse-swizzled global chunk = (tid&3) ^ ((tid>>3)&3).
    const int srow = tid >> 2;
    const int sgch = (tid & 3) ^ ((tid >> 3) & 3);
    const __bf16* Ags = A  + (size_t)(m0   + srow) * KDIM + sgch * 8;
    const __bf16* Bgs = Wt + (size_t)(cat0 + srow) * KDIM + sgch * 8;
    char* ldsw = smem + wave * 1024;   // + lane*16 implicit in global_load_lds

#define STG(o, h, kt, b) do { \
    const __bf16* gp_ = ((o) ? Bgs : Ags) + (size_t)(h) * 128 * KDIM + (kt) * 64; \
    char* lp_ = ldsw + (b) * 65536 + (o) * 32768 + (h) * 16384; \
    async_cp16(gp_,      lp_); \
    async_cp16(gp_ + 32, lp_ + 8192); \
} while (0)

    // ---- fragment read offsets: row r, k-chunk c -> byte r*64 + (c^((r>>1)&3))*16
    const int swz   = (quad ^ ((l15 >> 1) & 3)) * 16;
    const int abase = wm * 16384 + l15 * 64 + swz;
    const int bbase = 32768 + (wn >> 1) * 16384 + ((wn & 1) * 64 + l15) * 64 + swz;

    f32x4 acc[8][4];
    #pragma unroll
    for (int i = 0; i < 8; ++i)
        #pragma unroll
        for (int j = 0; j < 4; ++j) acc[i][j] = (f32x4){0.f, 0.f, 0.f, 0.f};

    bf16x8 af[4][2];   // current m-quadrant (4 frags x 2 ks)
    bf16x8 bf[4][2];   // all 4 n-frags x 2 ks

    auto LDA = [&](int mh, int bufb) {
        const char* p = smem + bufb + abase + mh * 4096;
        #pragma unroll
        for (int m = 0; m < 4; ++m) {
            af[m][0] = *(const bf16x8*)(p + m * 1024);
            af[m][1] = *(const bf16x8*)(p + m * 1024 + 8192);
        }
    };
    auto LDB = [&](int nh, int bufb) {
        const char* p = smem + bufb + bbase + nh * 2048;
        #pragma unroll
        for (int n = 0; n < 2; ++n) {
            bf[nh * 2 + n][0] = *(const bf16x8*)(p + n * 1024);
            bf[nh * 2 + n][1] = *(const bf16x8*)(p + n * 1024 + 8192);
        }
    };
    auto MMA = [&](int mh, int nh) {
        #pragma unroll
        for (int m = 0; m < 4; ++m)
            #pragma unroll
            for (int n = 0; n < 2; ++n) {
                acc[mh * 4 + m][nh * 2 + n] = __builtin_amdgcn_mfma_f32_16x16x32_bf16(
                    af[m][0], bf[nh * 2 + n][0], acc[mh * 4 + m][nh * 2 + n], 0, 0, 0);
                acc[mh * 4 + m][nh * 2 + n] = __builtin_amdgcn_mfma_f32_16x16x32_bf16(
                    af[m][1], bf[nh * 2 + n][1], acc[mh * 4 + m][nh * 2 + n], 0, 0, 0);
            }
    };

    // ---- prologue: tile0 fully + tile1 h0 halves; keep tile1-h0 in flight
    STG(0, 0, 0, 0); STG(1, 0, 0, 0); STG(0, 1, 0, 0); STG(1, 1, 0, 0);
    STG(0, 0, 1, 1); STG(1, 0, 1, 1);
    asm volatile("s_waitcnt vmcnt(4)" ::: "memory");   // tile0 landed
    BARM;

    #pragma unroll 2
    for (int t = 0; t < NT; ++t) {
        const int b    = t & 1;
        const int bufb = b * 65536;
        // phase 0: quadrant (mh0, nh0); stage (t+1) A-h1 -> other buf
        LDA(0, bufb); LDB(0, bufb);
        if (t + 1 < NT) STG(0, 1, t + 1, b ^ 1);
        BARM; asm volatile("s_waitcnt lgkmcnt(0)" ::: "memory");
        __builtin_amdgcn_s_setprio(1); MMA(0, 0); __builtin_amdgcn_s_setprio(0);
        BARM;
        // phase 1: (mh0, nh1); stage (t+1) B-h1
        LDB(1, bufb);
        if (t + 1 < NT) STG(1, 1, t + 1, b ^ 1);
        BARM; asm volatile("s_waitcnt lgkmcnt(0)" ::: "memory");
        __builtin_amdgcn_s_setprio(1); MMA(0, 1); __builtin_amdgcn_s_setprio(0);
        BARM;
        // phase 2: (mh1, nh0); no stage
        LDA(1, bufb);
        BARM; asm volatile("s_waitcnt lgkmcnt(0)" ::: "memory");
        __builtin_amdgcn_s_setprio(1); MMA(1, 0); __builtin_amdgcn_s_setprio(0);
        BARM;
        // phase 3: (mh1, nh1); stage (t+2) h0 halves into cur buf (now free);
        // boundary vmcnt BEFORE barrier -> publishes tile t+1 cross-wave.
        if (t + 2 < NT) { STG(0, 0, t + 2, b); STG(1, 0, t + 2, b); }
        if (t < NT - 2) { asm volatile("s_waitcnt vmcnt(4)" ::: "memory"); }
        else            { asm volatile("s_waitcnt vmcnt(0)" ::: "memory"); }
        BARM;
        __builtin_amdgcn_s_setprio(1); MMA(1, 1); __builtin_amdgcn_s_setprio(0);
        BARM;
    }

    // ---- epilogue: 4 passes of 64 m-rows; Ep[64][258] f32 (66KB, 2-way banks)
    float* Ep = (float*)smem;
    const int nn = tid & 63;
    const float bvi = b_i[n0 + nn], bvf = b_f[n0 + nn];
    const float bvo = b_o[n0 + nn], bvg = b_g[n0 + nn];
    int colW[4];
    #pragma unroll
    for (int nt = 0; nt < 4; ++nt)
        colW[nt] = ((wn & 1) * 2 + (nt >> 1)) * 64 + (wn >> 1) * 32 + (nt & 1) * 16 + l15;

    #pragma unroll
    for (int ch = 0; ch < 4; ++ch) {
        __syncthreads();
        if (wm == (ch >> 1)) {
            #pragma unroll
            for (int mi = 0; mi < 4; ++mi) {
                const int mt = (ch & 1) * 4 + mi;
                #pragma unroll
                for (int nt = 0; nt < 4; ++nt)
                    #pragma unroll
                    for (int r = 0; r < 4; ++r)
                        Ep[(mi * 16 + quad * 4 + r) * 258 + colW[nt]] = acc[mt][nt][r];
            }
        }
        __syncthreads();
        #pragma unroll
        for (int e = 0; e < 8; ++e) {
            const int row = e * 8 + wave;
            const float gi = sigm(Ep[row * 258 + nn] + bvi);
            const float gf = sigm(Ep[row * 258 + 64 + nn] + bvf);
            const float go = sigm(Ep[row * 258 + 128 + nn] + bvo);
            const float gg = tanh_fast(Ep[row * 258 + 192 + nn] + bvg);
            const size_t pos = (size_t)(m0 + ch * 64 + row) * NDIM + n0 + nn;
            const float cp = c_prev[pos];
            const float cv = gf * cp + gi * gg;
            out[pos] = go * tanh_fast(cv);                 // h
            out[(size_t)BDIM * NDIM + pos] = cv;           // c
        }
    }
#undef STG
}

extern "C" void kernel_launch(void* const* d_in, const int* in_sizes, int n_in,
                              void* d_out, int out_size, void* d_ws, size_t ws_size,
                              hipStream_t stream) {
    const float* Z  = (const float*)d_in[0];
    const float* H  = (const float*)d_in[1];
    const float* Cp = (const float*)d_in[2];
    const float* Wi = (const float*)d_in[3];
    const float* bi = (const float*)d_in[4];
    const float* Wf = (const float*)d_in[5];
    const float* bf = (const float*)d_in[6];
    const float* Wo = (const float*)d_in[7];
    const float* bo = (const float*)d_in[8];
    const float* Wg = (const float*)d_in[9];
    const float* bg = (const float*)d_in[10];

    __bf16* Acomb = (__bf16*)d_ws;                              // 32 MB
    __bf16* Wt    = (__bf16*)((char*)d_ws + (size_t)33554432);  // 16 MB

    static bool cfg = false;
    if (!cfg) {
        hipFuncSetAttribute(reinterpret_cast<const void*>(lstm_gemm_kernel),
                            hipFuncAttributeMaxDynamicSharedMemorySize, 131072);
        cfg = true;
    }

    prep_kernel<<<10240, 256, 0, stream>>>(Z, H, Wi, Wf, Wo, Wg, Acomb, Wt);
    lstm_gemm_kernel<<<512, 512, 131072, stream>>>(
        Acomb, Wt, bi, bf, bo, bg, Cp, (float*)d_out);
}